// Round 1
// baseline (859.261 us; speedup 1.0000x reference)
//
#include <hip/hip_runtime.h>

#define HDIM 768

constexpr int KC    = 64;          // k-chunk staged per iteration
constexpr int NCH   = HDIM / KC;   // 12 chunks
constexpr int ROWS  = 256;         // rows (samples) per block
constexpr int PITCH = KC + 4;      // 68 floats: 272B row pitch, 16B-aligned, bank-stride 4

__device__ __forceinline__ void dot4(float& a, const float4 xv,
                                     const float* __restrict__ Wrow, int kb) {
    const float4 w = *(const float4*)(Wrow + kb);   // wave-uniform -> s_load_dwordx4
    a = fmaf(xv.x, w.x, a);
    a = fmaf(xv.y, w.y, a);
    a = fmaf(xv.z, w.z, a);
    a = fmaf(xv.w, w.w, a);
}

__global__ __launch_bounds__(256, 2)
void hier_fused(const float* __restrict__ x,
                const float* __restrict__ Wa,  const float* __restrict__ ba,
                const float* __restrict__ Wb,  const float* __restrict__ bb,
                const float* __restrict__ Wc1, const float* __restrict__ bc1,
                const float* __restrict__ Wc2, const float* __restrict__ bc2,
                const float* __restrict__ Wc3, const float* __restrict__ bc3,
                const float* __restrict__ Wc4, const float* __restrict__ bc4,
                float* __restrict__ out, int B)
{
    __shared__ float xs[ROWS * PITCH];   // 256 * 68 * 4B = 68 KB -> 2 blocks/CU

    const int t       = threadIdx.x;
    const int rowBase = blockIdx.x * ROWS;

    float acc[17];
#pragma unroll
    for (int j = 0; j < 17; ++j) acc[j] = 0.f;

    const int f4   = (t & 15) * 4;   // float offset within the 64-float chunk
    const int rsub = t >> 4;         // 0..15

    for (int c = 0; c < NCH; ++c) {
        const int kc = c * KC;
        __syncthreads();             // previous chunk's compute done before overwrite
        // Stage 256 rows x 64 floats, coalesced: 16 consecutive lanes cover one
        // row's 256B segment; a wave covers 4 consecutive rows.
#pragma unroll
        for (int i = 0; i < 16; ++i) {
            int r   = rsub + i * 16;                    // 0..255
            int row = rowBase + r;
            if (row >= B) row = B - 1;                  // safe clamp (B % 256 == 0 normally)
            const float4 v = *(const float4*)&x[(size_t)row * HDIM + kc + f4];
            *(float4*)&xs[r * PITCH + f4] = v;
        }
        __syncthreads();

        // Compute: thread t owns row (rowBase + t); lane LDS stride = 68 floats
        // -> bank stride 4, conflict-free for ds_read_b128.
        const float* xr = &xs[t * PITCH];
#pragma unroll 4
        for (int kk = 0; kk < KC; kk += 4) {
            const float4 xv = *(const float4*)(xr + kk);
            const int kb = kc + kk;
            dot4(acc[0],  xv, Wa,              kb);
            dot4(acc[1],  xv, Wa  +     HDIM,  kb);
            dot4(acc[2],  xv, Wb,              kb);
            dot4(acc[3],  xv, Wb  +     HDIM,  kb);
            dot4(acc[4],  xv, Wb  + 2 * HDIM,  kb);
            dot4(acc[5],  xv, Wb  + 3 * HDIM,  kb);
            dot4(acc[6],  xv, Wc1,             kb);
            dot4(acc[7],  xv, Wc1 +     HDIM,  kb);
            dot4(acc[8],  xv, Wc2,             kb);
            dot4(acc[9],  xv, Wc2 +     HDIM,  kb);
            dot4(acc[10], xv, Wc2 + 2 * HDIM,  kb);
            dot4(acc[11], xv, Wc3,             kb);
            dot4(acc[12], xv, Wc3 +     HDIM,  kb);
            dot4(acc[13], xv, Wc3 + 2 * HDIM,  kb);
            dot4(acc[14], xv, Wc3 + 3 * HDIM,  kb);
            dot4(acc[15], xv, Wc4,             kb);
            dot4(acc[16], xv, Wc4 +     HDIM,  kb);
        }
    }

    const int row = rowBase + t;
    if (row >= B) return;

    // taskA head + route
    const float oa0 = acc[0] + ba[0];
    const float oa1 = acc[1] + ba[1];
    const bool active = oa1 > oa0;               // argmax != 0 (first-max tie -> 0)

    // taskB head
    const float tb0 = acc[2] + bb[0];
    const float tb1 = acc[3] + bb[1];
    const float tb2 = acc[4] + bb[2];
    const float tb3 = acc[5] + bb[3];
    int   p = 0;
    float m = tb0;
    if (tb1 > m) { m = tb1; p = 1; }             // strict > == first-occurrence argmax
    if (tb2 > m) { m = tb2; p = 2; }
    if (tb3 > m) { m = tb3; p = 3; }

    // out_a [B,2] at offset 0
    float* oa = out + (size_t)2 * row;
    oa[0] = oa0;
    oa[1] = oa1;

    // out_b [B,5] at offset 2B
    float* ob = out + (size_t)2 * B + (size_t)5 * row;
    ob[0] = 0.f;
    ob[1] = active ? tb0 : 0.f;
    ob[2] = active ? tb1 : 0.f;
    ob[3] = active ? tb2 : 0.f;
    ob[4] = active ? tb3 : 0.f;

    // out_c [B,11] at offset 7B; head col spans: h0:[0,2) h1:[2,5) h2:[5,9) h3:[9,11)
    const bool m0 = active && (p == 0);
    const bool m1 = active && (p == 1);
    const bool m2 = active && (p == 2);
    const bool m3 = active && (p == 3);
    float* oc = out + (size_t)7 * B + (size_t)11 * row;
    oc[0]  = m0 ? acc[6]  + bc1[0] : 0.f;
    oc[1]  = m0 ? acc[7]  + bc1[1] : 0.f;
    oc[2]  = m1 ? acc[8]  + bc2[0] : 0.f;
    oc[3]  = m1 ? acc[9]  + bc2[1] : 0.f;
    oc[4]  = m1 ? acc[10] + bc2[2] : 0.f;
    oc[5]  = m2 ? acc[11] + bc3[0] : 0.f;
    oc[6]  = m2 ? acc[12] + bc3[1] : 0.f;
    oc[7]  = m2 ? acc[13] + bc3[2] : 0.f;
    oc[8]  = m2 ? acc[14] + bc3[3] : 0.f;
    oc[9]  = m3 ? acc[15] + bc4[0] : 0.f;
    oc[10] = m3 ? acc[16] + bc4[1] : 0.f;
}

extern "C" void kernel_launch(void* const* d_in, const int* in_sizes, int n_in,
                              void* d_out, int out_size, void* d_ws, size_t ws_size,
                              hipStream_t stream) {
    const float* x   = (const float*)d_in[0];
    const float* Wa  = (const float*)d_in[1];
    const float* ba  = (const float*)d_in[2];
    const float* Wb  = (const float*)d_in[3];
    const float* bb  = (const float*)d_in[4];
    const float* Wc1 = (const float*)d_in[5];
    const float* bc1 = (const float*)d_in[6];
    const float* Wc2 = (const float*)d_in[7];
    const float* bc2 = (const float*)d_in[8];
    const float* Wc3 = (const float*)d_in[9];
    const float* bc3 = (const float*)d_in[10];
    const float* Wc4 = (const float*)d_in[11];
    const float* bc4 = (const float*)d_in[12];

    const int B  = in_sizes[0] / HDIM;
    const int nb = (B + ROWS - 1) / ROWS;

    hipLaunchKernelGGL(hier_fused, dim3(nb), dim3(256), 0, stream,
                       x, Wa, ba, Wb, bb, Wc1, bc1, Wc2, bc2, Wc3, bc3, Wc4, bc4,
                       (float*)d_out, B);
}

// Round 2
// 673.134 us; speedup vs baseline: 1.2765x; 1.2765x over previous
//
#include <hip/hip_runtime.h>

#define HDIM 768

constexpr int KC    = 32;          // k-columns per K-half staged per chunk
constexpr int KHALF = HDIM / 2;    // 384
constexpr int NCH   = KHALF / KC;  // 12 chunks
constexpr int RPB   = 128;         // rows per block
constexpr int PITCH = 2 * KC + 4;  // 68 floats: 272B pitch, 16B-aligned, conflict-free (verified R1)

__device__ __forceinline__ void dot4(float& a, const float4 xv,
                                     const float* __restrict__ Wrow, int kb) {
    // kb carries an opaque VGPR zero -> compiler must keep this a VECTOR load
    // (global_load_dwordx4, in-order vmcnt) instead of scalarizing to s_load
    // batches that blow the SGPR budget and force lgkmcnt(0) drains.
    const float4 w = *(const float4*)(Wrow + kb);
    a = fmaf(xv.x, w.x, a);
    a = fmaf(xv.y, w.y, a);
    a = fmaf(xv.z, w.z, a);
    a = fmaf(xv.w, w.w, a);
}

__global__ __launch_bounds__(256, 4)
void hier_fused(const float* __restrict__ x,
                const float* __restrict__ Wa,  const float* __restrict__ ba,
                const float* __restrict__ Wb,  const float* __restrict__ bb,
                const float* __restrict__ Wc1, const float* __restrict__ bc1,
                const float* __restrict__ Wc2, const float* __restrict__ bc2,
                const float* __restrict__ Wc3, const float* __restrict__ bc3,
                const float* __restrict__ Wc4, const float* __restrict__ bc4,
                float* __restrict__ out, int B)
{
    __shared__ float xs[RPB * PITCH];   // 128*68*4 = 34816 B -> 4 blocks/CU

    const int t       = threadIdx.x;
    const int r       = t & (RPB - 1);  // row within block
    const int kh      = t >> 7;         // K-half: 0 -> k[0,384), 1 -> k[384,768)
    const int rowBase = blockIdx.x * RPB;

    int vz;
    asm("v_mov_b32 %0, 0" : "=v"(vz));  // opaque zero: defeats scalar-load promotion

    float acc[17];
#pragma unroll
    for (int j = 0; j < 17; ++j) acc[j] = 0.f;

    // staging map: 16 consecutive lanes cover one row's 64 staged floats
    const int col4 = (t & 15) * 4;                      // 0..60
    const int grp  = t >> 4;                            // 0..15
    const int gOff = (col4 < KC) ? col4                 // half-0 slice
                                 : (KHALF - KC + col4); // half-1 slice

    for (int c = 0; c < NCH; ++c) {
        __syncthreads();                 // previous chunk's compute done
        const int gcol = c * KC + gOff;
#pragma unroll
        for (int i = 0; i < 8; ++i) {
            int r2  = grp + i * 16;                     // 0..127
            int row = rowBase + r2;
            if (row >= B) row = B - 1;
            const float4 v = *(const float4*)&x[(size_t)row * HDIM + gcol];
            *(float4*)&xs[r2 * PITCH + col4] = v;
        }
        __syncthreads();

        const float* xr    = &xs[r * PITCH + kh * KC];
        const int    kbase = kh * KHALF + c * KC + vz;
#pragma unroll 2
        for (int kk = 0; kk < KC; kk += 4) {
            const float4 xv = *(const float4*)(xr + kk);
            const int kb = kbase + kk;
            dot4(acc[0],  xv, Wa,              kb);
            dot4(acc[1],  xv, Wa  +     HDIM,  kb);
            dot4(acc[2],  xv, Wb,              kb);
            dot4(acc[3],  xv, Wb  +     HDIM,  kb);
            dot4(acc[4],  xv, Wb  + 2 * HDIM,  kb);
            dot4(acc[5],  xv, Wb  + 3 * HDIM,  kb);
            dot4(acc[6],  xv, Wc1,             kb);
            dot4(acc[7],  xv, Wc1 +     HDIM,  kb);
            dot4(acc[8],  xv, Wc2,             kb);
            dot4(acc[9],  xv, Wc2 +     HDIM,  kb);
            dot4(acc[10], xv, Wc2 + 2 * HDIM,  kb);
            dot4(acc[11], xv, Wc3,             kb);
            dot4(acc[12], xv, Wc3 +     HDIM,  kb);
            dot4(acc[13], xv, Wc3 + 2 * HDIM,  kb);
            dot4(acc[14], xv, Wc3 + 3 * HDIM,  kb);
            dot4(acc[15], xv, Wc4,             kb);
            dot4(acc[16], xv, Wc4 +     HDIM,  kb);
        }
    }

    // combine the two K-half partials through LDS (xs is dead now)
    __syncthreads();
    if (kh == 1) {
#pragma unroll
        for (int j = 0; j < 17; ++j) xs[r * 18 + j] = acc[j];
    }
    __syncthreads();
    if (kh != 0) return;

#pragma unroll
    for (int j = 0; j < 17; ++j) acc[j] += xs[r * 18 + j];

    const int row = rowBase + r;
    if (row >= B) return;

    // taskA head + route (fp32-exact routing)
    const float oa0 = acc[0] + ba[0];
    const float oa1 = acc[1] + ba[1];
    const bool active = oa1 > oa0;               // argmax != 0 (first-max tie -> 0)

    // taskB head
    const float tb0 = acc[2] + bb[0];
    const float tb1 = acc[3] + bb[1];
    const float tb2 = acc[4] + bb[2];
    const float tb3 = acc[5] + bb[3];
    int   p = 0;
    float m = tb0;
    if (tb1 > m) { m = tb1; p = 1; }             // strict > == first-occurrence argmax
    if (tb2 > m) { m = tb2; p = 2; }
    if (tb3 > m) { m = tb3; p = 3; }

    // out_a [B,2] at offset 0
    float* oa = out + (size_t)2 * row;
    oa[0] = oa0;
    oa[1] = oa1;

    // out_b [B,5] at offset 2B
    float* ob = out + (size_t)2 * B + (size_t)5 * row;
    ob[0] = 0.f;
    ob[1] = active ? tb0 : 0.f;
    ob[2] = active ? tb1 : 0.f;
    ob[3] = active ? tb2 : 0.f;
    ob[4] = active ? tb3 : 0.f;

    // out_c [B,11] at offset 7B; spans h0:[0,2) h1:[2,5) h2:[5,9) h3:[9,11)
    const bool m0 = active && (p == 0);
    const bool m1 = active && (p == 1);
    const bool m2 = active && (p == 2);
    const bool m3 = active && (p == 3);
    float* oc = out + (size_t)7 * B + (size_t)11 * row;
    oc[0]  = m0 ? acc[6]  + bc1[0] : 0.f;
    oc[1]  = m0 ? acc[7]  + bc1[1] : 0.f;
    oc[2]  = m1 ? acc[8]  + bc2[0] : 0.f;
    oc[3]  = m1 ? acc[9]  + bc2[1] : 0.f;
    oc[4]  = m1 ? acc[10] + bc2[2] : 0.f;
    oc[5]  = m2 ? acc[11] + bc3[0] : 0.f;
    oc[6]  = m2 ? acc[12] + bc3[1] : 0.f;
    oc[7]  = m2 ? acc[13] + bc3[2] : 0.f;
    oc[8]  = m2 ? acc[14] + bc3[3] : 0.f;
    oc[9]  = m3 ? acc[15] + bc4[0] : 0.f;
    oc[10] = m3 ? acc[16] + bc4[1] : 0.f;
}

extern "C" void kernel_launch(void* const* d_in, const int* in_sizes, int n_in,
                              void* d_out, int out_size, void* d_ws, size_t ws_size,
                              hipStream_t stream) {
    const float* x   = (const float*)d_in[0];
    const float* Wa  = (const float*)d_in[1];
    const float* ba  = (const float*)d_in[2];
    const float* Wb  = (const float*)d_in[3];
    const float* bb  = (const float*)d_in[4];
    const float* Wc1 = (const float*)d_in[5];
    const float* bc1 = (const float*)d_in[6];
    const float* Wc2 = (const float*)d_in[7];
    const float* bc2 = (const float*)d_in[8];
    const float* Wc3 = (const float*)d_in[9];
    const float* bc3 = (const float*)d_in[10];
    const float* Wc4 = (const float*)d_in[11];
    const float* bc4 = (const float*)d_in[12];

    const int B  = in_sizes[0] / HDIM;
    const int nb = (B + RPB - 1) / RPB;

    hipLaunchKernelGGL(hier_fused, dim3(nb), dim3(256), 0, stream,
                       x, Wa, ba, Wb, bb, Wc1, bc1, Wc2, bc2, Wc3, bc3, Wc4, bc4,
                       (float*)d_out, B);
}